// Round 1
// baseline (4752.526 us; speedup 1.0000x reference)
//
#include <hip/hip_runtime.h>
#include <math.h>

#define NND 50000
#define NED 800000
#define HD  128
#define NG  64

__device__ __forceinline__ float gelu_t(float x) {
  const float c = 0.7978845608028654f;
  float t = tanhf(c * (x + 0.044715f * x * x * x));
  return 0.5f * x * (1.0f + t);
}

// ---------------- CSR build ----------------
__global__ void k_hist(const int* __restrict__ dst, int* __restrict__ degi) {
  int e = blockIdx.x * 256 + threadIdx.x;
  if (e < NED) atomicAdd(&degi[dst[e]], 1);
}

__global__ void k_scan(const int* __restrict__ degi, int* __restrict__ rowptr,
                       int* __restrict__ cursor, float* __restrict__ deginv) {
  __shared__ int sh[1024];
  int tid = threadIdx.x;
  int running = 0;
  for (int base = 0; base < NND; base += 1024) {
    int idx = base + tid;
    int v = (idx < NND) ? degi[idx] : 0;
    sh[tid] = v;
    __syncthreads();
    for (int off = 1; off < 1024; off <<= 1) {
      int t = (tid >= off) ? sh[tid - off] : 0;
      __syncthreads();
      sh[tid] += t;
      __syncthreads();
    }
    int excl = running + sh[tid] - v;
    if (idx < NND) {
      rowptr[idx] = excl;
      cursor[idx] = excl;
      deginv[idx] = 1.0f / (float)max(v, 1);
    }
    int tot = sh[1023];
    __syncthreads();
    running += tot;
  }
  if (tid == 0) rowptr[NND] = running;
}

__global__ void k_scatter(const int* __restrict__ src, const int* __restrict__ dst,
                          int* __restrict__ cursor, int* __restrict__ csrsrc) {
  int e = blockIdx.x * 256 + threadIdx.x;
  if (e < NED) {
    int d = dst[e];
    int pos = atomicAdd(&cursor[d], 1);
    csrsrc[pos] = src[e];
  }
}

__global__ void k_count(const int* __restrict__ batch, float* __restrict__ cnt) {
  int i = blockIdx.x * 256 + threadIdx.x;
  if (i < NND) atomicAdd(&cnt[batch[i]], 1.0f);
}

__global__ void k_weff(const float* __restrict__ Wint, float* __restrict__ weff) {
  int i = blockIdx.x * 256 + threadIdx.x;
  if (i < HD * HD) weff[i] = Wint[i] + Wint[i + HD * HD];
}

// ---------------- init: h = w0*gelu(LN(x@Win+b)) + w1*gelu(LN(x@Walt+b)) ----------------
__global__ __launch_bounds__(256) void k_init(
    const float* __restrict__ x,
    const float* __restrict__ Win, const float* __restrict__ bin,
    const float* __restrict__ gin, const float* __restrict__ bein,
    const float* __restrict__ Walt, const float* __restrict__ balt,
    const float* __restrict__ galt, const float* __restrict__ bealt,
    const float* __restrict__ alphap, const float* __restrict__ betap,
    float* __restrict__ hdst)
{
  __shared__ float As[32][16];
  __shared__ float Bs[16][256];
  int tid = threadIdx.x;
  int lane = tid & 63;
  int ty = tid >> 6;  // 0..3, 8 rows each
  int rowBase = blockIdx.x * 32;
  float acc[8][4];
#pragma unroll
  for (int i = 0; i < 8; ++i) { acc[i][0]=0.f; acc[i][1]=0.f; acc[i][2]=0.f; acc[i][3]=0.f; }

  for (int kc = 0; kc < 8; ++kc) {
    int k0 = kc * 16;
    if (tid < 128) {
      int r = tid >> 2, kq = (tid & 3) * 4;
      int row = rowBase + r; if (row >= NND) row = NND - 1;
      *(float4*)&As[r][kq] = *(const float4*)&x[(size_t)row * HD + k0 + kq];
    }
#pragma unroll
    for (int p = 0; p < 4; ++p) {
      int idx = p * 256 + tid;
      int kk = idx >> 6, cq = idx & 63;
      int col = cq * 4;
      int k = k0 + kk;
      const float* srcp = (col < HD) ? &Win[k * HD + col] : &Walt[k * HD + (col - HD)];
      *(float4*)&Bs[kk][col] = *(const float4*)srcp;
    }
    __syncthreads();
#pragma unroll
    for (int kq = 0; kq < 4; ++kq) {
      float4 b0 = *(float4*)&Bs[kq*4+0][lane*4];
      float4 b1 = *(float4*)&Bs[kq*4+1][lane*4];
      float4 b2 = *(float4*)&Bs[kq*4+2][lane*4];
      float4 b3 = *(float4*)&Bs[kq*4+3][lane*4];
#pragma unroll
      for (int i = 0; i < 8; ++i) {
        float4 a = *(float4*)&As[ty*8+i][kq*4];
        acc[i][0] = fmaf(a.x,b0.x,fmaf(a.y,b1.x,fmaf(a.z,b2.x,fmaf(a.w,b3.x,acc[i][0]))));
        acc[i][1] = fmaf(a.x,b0.y,fmaf(a.y,b1.y,fmaf(a.z,b2.y,fmaf(a.w,b3.y,acc[i][1]))));
        acc[i][2] = fmaf(a.x,b0.z,fmaf(a.y,b1.z,fmaf(a.z,b2.z,fmaf(a.w,b3.z,acc[i][2]))));
        acc[i][3] = fmaf(a.x,b0.w,fmaf(a.y,b1.w,fmaf(a.z,b2.w,fmaf(a.w,b3.w,acc[i][3]))));
      }
    }
    __syncthreads();
  }

  float al = alphap[0], bt = betap[0];
  float nrm = sqrtf(al*al + bt*bt);
  float w0 = fabsf(al) / nrm, w1 = fabsf(bt) / nrm;
  int path = lane >> 5;
  int cl = (lane & 31) * 4;
  const float* bvp = path ? balt : bin;
  const float* gp  = path ? galt : gin;
  const float* bep = path ? bealt : bein;
  float4 bv  = *(const float4*)&bvp[cl];
  float4 gv  = *(const float4*)&gp[cl];
  float4 bev = *(const float4*)&bep[cl];
#pragma unroll
  for (int i = 0; i < 8; ++i) {
    int row = rowBase + ty*8 + i;
    float z0 = acc[i][0]+bv.x, z1 = acc[i][1]+bv.y, z2 = acc[i][2]+bv.z, z3 = acc[i][3]+bv.w;
    float rsum = z0+z1+z2+z3;
    float rsq  = z0*z0+z1*z1+z2*z2+z3*z3;
#pragma unroll
    for (int m = 1; m < 32; m <<= 1) { rsum += __shfl_xor(rsum, m, 32); rsq += __shfl_xor(rsq, m, 32); }
    float mean = rsum * (1.0f/128.0f);
    float var  = rsq * (1.0f/128.0f) - mean*mean;
    float rs = rsqrtf(var + 1e-5f);
    float g0 = gelu_t((z0-mean)*rs*gv.x + bev.x);
    float g1 = gelu_t((z1-mean)*rs*gv.y + bev.y);
    float g2 = gelu_t((z2-mean)*rs*gv.z + bev.z);
    float g3 = gelu_t((z3-mean)*rs*gv.w + bev.w);
    float o0 = __shfl_xor(g0, 32, 64);
    float o1 = __shfl_xor(g1, 32, 64);
    float o2 = __shfl_xor(g2, 32, 64);
    float o3 = __shfl_xor(g3, 32, 64);
    float h0 = (path==0) ? fmaf(w0,g0,w1*o0) : fmaf(w0,o0,w1*g0);
    float h1 = (path==0) ? fmaf(w0,g1,w1*o1) : fmaf(w0,o1,w1*g1);
    float h2 = (path==0) ? fmaf(w0,g2,w1*o2) : fmaf(w0,o2,w1*g2);
    float h3 = (path==0) ? fmaf(w0,g3,w1*o3) : fmaf(w0,o3,w1*g3);
    if (row < NND && path == 0) {
      float4 hw = make_float4(h0, h1, h2, h3);
      *(float4*)&hdst[(size_t)row * HD + cl] = hw;
    }
  }
}

// ---------------- SpMM: u[i] = (sum_{j->i} yin[j]) * deginv[i] ----------------
__global__ __launch_bounds__(256) void k_spmm(
    const float* __restrict__ yin, const int* __restrict__ rowptr,
    const int* __restrict__ csrsrc, const float* __restrict__ deginv,
    float* __restrict__ u)
{
  int tid = threadIdx.x;
  int node = blockIdx.x * 8 + (tid >> 5);
  int lane = tid & 31;
  if (node >= NND) return;
  int e0 = rowptr[node], e1 = rowptr[node + 1];
  float4 acc = make_float4(0.f, 0.f, 0.f, 0.f);
  for (int e = e0; e < e1; ++e) {
    int s = csrsrc[e];
    float4 v = *(const float4*)&yin[(size_t)s * HD + lane * 4];
    acc.x += v.x; acc.y += v.y; acc.z += v.z; acc.w += v.w;
  }
  float di = deginv[node];
  acc.x *= di; acc.y *= di; acc.z *= di; acc.w *= di;
  *(float4*)&u[(size_t)node * HD + lane * 4] = acc;
}

// ---------------- ODE GEMM + RK4 epilogue ----------------
// k = tanh([ain|u] @ [Wself;Wmsg] + bode);   stage-dependent kacc / y|h update
__global__ __launch_bounds__(256) void k_ode(
    const float* __restrict__ ain, const float* __restrict__ u,
    const float* __restrict__ Wself, const float* __restrict__ Wmsg,
    const float* __restrict__ bode,
    const float* __restrict__ h, float* __restrict__ kacc,
    float* __restrict__ yout, int stage)
{
  __shared__ float As[64][16];
  __shared__ float Bs[16][128];
  int tid = threadIdx.x;
  int tx = tid & 31, ty = tid >> 5;
  int rowBase = blockIdx.x * 64;
  float acc[8][4];
#pragma unroll
  for (int i = 0; i < 8; ++i) { acc[i][0]=0.f; acc[i][1]=0.f; acc[i][2]=0.f; acc[i][3]=0.f; }

  for (int kc = 0; kc < 16; ++kc) {
    int k0 = kc * 16;
    {
      int r = tid >> 2, kq = (tid & 3) * 4;
      int row = rowBase + r; if (row >= NND) row = NND - 1;
      const float* srcp = (k0 < HD) ? &ain[(size_t)row * HD + k0 + kq]
                                    : &u[(size_t)row * HD + (k0 - HD) + kq];
      *(float4*)&As[r][kq] = *(const float4*)srcp;
    }
#pragma unroll
    for (int j = 0; j < 2; ++j) {
      int kk = (tid >> 5) + j * 8;
      int n = (tid & 31) * 4;
      int k = k0 + kk;
      const float* srcp = (k < HD) ? &Wself[k * HD + n] : &Wmsg[(k - HD) * HD + n];
      *(float4*)&Bs[kk][n] = *(const float4*)srcp;
    }
    __syncthreads();
#pragma unroll
    for (int kq = 0; kq < 4; ++kq) {
      float4 b0 = *(float4*)&Bs[kq*4+0][tx*4];
      float4 b1 = *(float4*)&Bs[kq*4+1][tx*4];
      float4 b2 = *(float4*)&Bs[kq*4+2][tx*4];
      float4 b3 = *(float4*)&Bs[kq*4+3][tx*4];
#pragma unroll
      for (int i = 0; i < 8; ++i) {
        float4 a = *(float4*)&As[ty*8+i][kq*4];
        acc[i][0] = fmaf(a.x,b0.x,fmaf(a.y,b1.x,fmaf(a.z,b2.x,fmaf(a.w,b3.x,acc[i][0]))));
        acc[i][1] = fmaf(a.x,b0.y,fmaf(a.y,b1.y,fmaf(a.z,b2.y,fmaf(a.w,b3.y,acc[i][1]))));
        acc[i][2] = fmaf(a.x,b0.z,fmaf(a.y,b1.z,fmaf(a.z,b2.z,fmaf(a.w,b3.z,acc[i][2]))));
        acc[i][3] = fmaf(a.x,b0.w,fmaf(a.y,b1.w,fmaf(a.z,b2.w,fmaf(a.w,b3.w,acc[i][3]))));
      }
    }
    __syncthreads();
  }

  const float DT = 0.125f;
  float wk = (stage == 0 || stage == 3) ? DT / 6.0f : DT / 3.0f;
  float cy = (stage <= 1) ? 0.5f * DT : DT;
  int c0 = tx * 4;
  float4 bo = *(const float4*)&bode[c0];
#pragma unroll
  for (int i = 0; i < 8; ++i) {
    int row = rowBase + ty*8 + i;
    if (row >= NND) continue;
    size_t off = (size_t)row * HD + c0;
    float v0 = tanhf(acc[i][0] + bo.x);
    float v1 = tanhf(acc[i][1] + bo.y);
    float v2 = tanhf(acc[i][2] + bo.z);
    float v3 = tanhf(acc[i][3] + bo.w);
    float4 ka;
    if (stage == 0) {
      ka = make_float4(wk*v0, wk*v1, wk*v2, wk*v3);
    } else {
      ka = *(const float4*)&kacc[off];
      ka.x += wk*v0; ka.y += wk*v1; ka.z += wk*v2; ka.w += wk*v3;
    }
    *(float4*)&kacc[off] = ka;
    float4 hv = *(const float4*)&h[off];
    float4 o;
    if (stage < 3) {
      o = make_float4(hv.x + cy*v0, hv.y + cy*v1, hv.z + cy*v2, hv.w + cy*v3);
    } else {
      o = make_float4(hv.x + ka.x, hv.y + ka.y, hv.z + ka.z, hv.w + ka.w);
    }
    *(float4*)&yout[off] = o;
  }
}

// ---------------- interference: h2 = (h + gate*tanh(LN(h@weff+bint))) * cscale ----------------
__global__ __launch_bounds__(256) void k_interf(
    const float* __restrict__ h, const float* __restrict__ weff,
    const float* __restrict__ bint, const float* __restrict__ gint,
    const float* __restrict__ beint,
    const float* __restrict__ alphap, const float* __restrict__ betap,
    const float* __restrict__ phasep,
    float* __restrict__ h2out)
{
  __shared__ float As[64][16];
  __shared__ float Bs[16][128];
  int tid = threadIdx.x;
  int tx = tid & 31, ty = tid >> 5;
  int rowBase = blockIdx.x * 64;
  float acc[8][4];
#pragma unroll
  for (int i = 0; i < 8; ++i) { acc[i][0]=0.f; acc[i][1]=0.f; acc[i][2]=0.f; acc[i][3]=0.f; }

  for (int kc = 0; kc < 8; ++kc) {
    int k0 = kc * 16;
    {
      int r = tid >> 2, kq = (tid & 3) * 4;
      int row = rowBase + r; if (row >= NND) row = NND - 1;
      *(float4*)&As[r][kq] = *(const float4*)&h[(size_t)row * HD + k0 + kq];
    }
#pragma unroll
    for (int j = 0; j < 2; ++j) {
      int kk = (tid >> 5) + j * 8;
      int n = (tid & 31) * 4;
      *(float4*)&Bs[kk][n] = *(const float4*)&weff[(k0 + kk) * HD + n];
    }
    __syncthreads();
#pragma unroll
    for (int kq = 0; kq < 4; ++kq) {
      float4 b0 = *(float4*)&Bs[kq*4+0][tx*4];
      float4 b1 = *(float4*)&Bs[kq*4+1][tx*4];
      float4 b2 = *(float4*)&Bs[kq*4+2][tx*4];
      float4 b3 = *(float4*)&Bs[kq*4+3][tx*4];
#pragma unroll
      for (int i = 0; i < 8; ++i) {
        float4 a = *(float4*)&As[ty*8+i][kq*4];
        acc[i][0] = fmaf(a.x,b0.x,fmaf(a.y,b1.x,fmaf(a.z,b2.x,fmaf(a.w,b3.x,acc[i][0]))));
        acc[i][1] = fmaf(a.x,b0.y,fmaf(a.y,b1.y,fmaf(a.z,b2.y,fmaf(a.w,b3.y,acc[i][1]))));
        acc[i][2] = fmaf(a.x,b0.z,fmaf(a.y,b1.z,fmaf(a.z,b2.z,fmaf(a.w,b3.z,acc[i][2]))));
        acc[i][3] = fmaf(a.x,b0.w,fmaf(a.y,b1.w,fmaf(a.z,b2.w,fmaf(a.w,b3.w,acc[i][3]))));
      }
    }
    __syncthreads();
  }

  float al = alphap[0], bt = betap[0], ph = phasep[0];
  float n2 = al*al + bt*bt;
  float p0 = (al*al) / n2, p1 = (bt*bt) / n2;
  float interf = 2.0f * sqrtf(p0 * p1) * cosf(ph);
  float gate = (fabsf(interf) > 0.01f) ? interf : 0.0f;
  float cscale = (p0 > p1) ? 1.0f : cosf(ph);

  int c0 = tx * 4;
  float4 bi  = *(const float4*)&bint[c0];
  float4 gv  = *(const float4*)&gint[c0];
  float4 bev = *(const float4*)&beint[c0];
#pragma unroll
  for (int i = 0; i < 8; ++i) {
    int row = rowBase + ty*8 + i;
    float z0 = acc[i][0]+bi.x, z1 = acc[i][1]+bi.y, z2 = acc[i][2]+bi.z, z3 = acc[i][3]+bi.w;
    float rsum = z0+z1+z2+z3;
    float rsq  = z0*z0+z1*z1+z2*z2+z3*z3;
#pragma unroll
    for (int m = 1; m < 32; m <<= 1) { rsum += __shfl_xor(rsum, m, 32); rsq += __shfl_xor(rsq, m, 32); }
    float mean = rsum * (1.0f/128.0f);
    float var  = rsq * (1.0f/128.0f) - mean*mean;
    float rs = rsqrtf(var + 1e-5f);
    float t0 = tanhf((z0-mean)*rs*gv.x + bev.x);
    float t1 = tanhf((z1-mean)*rs*gv.y + bev.y);
    float t2 = tanhf((z2-mean)*rs*gv.z + bev.z);
    float t3 = tanhf((z3-mean)*rs*gv.w + bev.w);
    if (row < NND) {
      size_t off = (size_t)row * HD + c0;
      float4 hv = *(const float4*)&h[off];
      float4 o = make_float4((hv.x + gate*t0) * cscale,
                             (hv.y + gate*t1) * cscale,
                             (hv.z + gate*t2) * cscale,
                             (hv.w + gate*t3) * cscale);
      *(float4*)&h2out[off] = o;
    }
  }
}

// ---------------- output GEMM + pooled atomic accumulation ----------------
__global__ __launch_bounds__(256) void k_out(
    const float* __restrict__ h2, const float* __restrict__ Wout,
    const float* __restrict__ bout, const int* __restrict__ batch,
    float* __restrict__ pooled)
{
  __shared__ float As[64][16];
  __shared__ float Bs[16][128];
  int tid = threadIdx.x;
  int tx = tid & 31, ty = tid >> 5;
  int rowBase = blockIdx.x * 64;
  float acc[8][4];
#pragma unroll
  for (int i = 0; i < 8; ++i) { acc[i][0]=0.f; acc[i][1]=0.f; acc[i][2]=0.f; acc[i][3]=0.f; }

  for (int kc = 0; kc < 8; ++kc) {
    int k0 = kc * 16;
    {
      int r = tid >> 2, kq = (tid & 3) * 4;
      int row = rowBase + r; if (row >= NND) row = NND - 1;
      *(float4*)&As[r][kq] = *(const float4*)&h2[(size_t)row * HD + k0 + kq];
    }
#pragma unroll
    for (int j = 0; j < 2; ++j) {
      int kk = (tid >> 5) + j * 8;
      int n = (tid & 31) * 4;
      *(float4*)&Bs[kk][n] = *(const float4*)&Wout[(k0 + kk) * HD + n];
    }
    __syncthreads();
#pragma unroll
    for (int kq = 0; kq < 4; ++kq) {
      float4 b0 = *(float4*)&Bs[kq*4+0][tx*4];
      float4 b1 = *(float4*)&Bs[kq*4+1][tx*4];
      float4 b2 = *(float4*)&Bs[kq*4+2][tx*4];
      float4 b3 = *(float4*)&Bs[kq*4+3][tx*4];
#pragma unroll
      for (int i = 0; i < 8; ++i) {
        float4 a = *(float4*)&As[ty*8+i][kq*4];
        acc[i][0] = fmaf(a.x,b0.x,fmaf(a.y,b1.x,fmaf(a.z,b2.x,fmaf(a.w,b3.x,acc[i][0]))));
        acc[i][1] = fmaf(a.x,b0.y,fmaf(a.y,b1.y,fmaf(a.z,b2.y,fmaf(a.w,b3.y,acc[i][1]))));
        acc[i][2] = fmaf(a.x,b0.z,fmaf(a.y,b1.z,fmaf(a.z,b2.z,fmaf(a.w,b3.z,acc[i][2]))));
        acc[i][3] = fmaf(a.x,b0.w,fmaf(a.y,b1.w,fmaf(a.z,b2.w,fmaf(a.w,b3.w,acc[i][3]))));
      }
    }
    __syncthreads();
  }

  int c0 = tx * 4;
  float4 bo = *(const float4*)&bout[c0];
  int prevg = -1;
  float r0 = 0.f, r1 = 0.f, r2 = 0.f, r3 = 0.f;
#pragma unroll
  for (int i = 0; i < 8; ++i) {
    int row = rowBase + ty*8 + i;
    if (row >= NND) break;
    int g = batch[row];
    float v0 = acc[i][0] + bo.x;
    float v1 = acc[i][1] + bo.y;
    float v2 = acc[i][2] + bo.z;
    float v3 = acc[i][3] + bo.w;
    if (g != prevg) {
      if (prevg >= 0) {
        atomicAdd(&pooled[prevg*HD + c0 + 0], r0);
        atomicAdd(&pooled[prevg*HD + c0 + 1], r1);
        atomicAdd(&pooled[prevg*HD + c0 + 2], r2);
        atomicAdd(&pooled[prevg*HD + c0 + 3], r3);
      }
      prevg = g; r0 = v0; r1 = v1; r2 = v2; r3 = v3;
    } else {
      r0 += v0; r1 += v1; r2 += v2; r3 += v3;
    }
  }
  if (prevg >= 0) {
    atomicAdd(&pooled[prevg*HD + c0 + 0], r0);
    atomicAdd(&pooled[prevg*HD + c0 + 1], r1);
    atomicAdd(&pooled[prevg*HD + c0 + 2], r2);
    atomicAdd(&pooled[prevg*HD + c0 + 3], r3);
  }
}

__global__ void k_final(const float* __restrict__ pooled, const float* __restrict__ cnt,
                        float* __restrict__ out) {
  int i = blockIdx.x * 256 + threadIdx.x;
  if (i < NG * HD) out[i] = pooled[i] / fmaxf(cnt[i >> 7], 1.0f);
}

extern "C" void kernel_launch(void* const* d_in, const int* in_sizes, int n_in,
                              void* d_out, int out_size, void* d_ws, size_t ws_size,
                              hipStream_t stream) {
  (void)in_sizes; (void)n_in; (void)out_size; (void)ws_size;
  const float* x     = (const float*)d_in[0];
  const int*   ei    = (const int*)d_in[1];
  const int*   batch = (const int*)d_in[2];
  const float* alpha = (const float*)d_in[3];
  const float* beta  = (const float*)d_in[4];
  const float* phase = (const float*)d_in[5];
  const float* Win   = (const float*)d_in[6];
  const float* bin   = (const float*)d_in[7];
  const float* gin   = (const float*)d_in[8];
  const float* bein  = (const float*)d_in[9];
  const float* Walt  = (const float*)d_in[10];
  const float* balt  = (const float*)d_in[11];
  const float* galt  = (const float*)d_in[12];
  const float* bealt = (const float*)d_in[13];
  const float* Wself = (const float*)d_in[14];
  const float* Wmsg  = (const float*)d_in[15];
  const float* bode  = (const float*)d_in[16];
  const float* Wint  = (const float*)d_in[17];
  const float* bint  = (const float*)d_in[18];
  const float* gint  = (const float*)d_in[19];
  const float* beint = (const float*)d_in[20];
  const float* Wout  = (const float*)d_in[21];
  const float* bout  = (const float*)d_in[22];
  float* out = (float*)d_out;

  const int* esrc = ei;
  const int* edst = ei + NED;

  size_t NH = (size_t)NND * HD;
  float* fws    = (float*)d_ws;
  float* h      = fws;
  float* y      = fws + NH;
  float* kacc   = fws + 2 * NH;
  float* u      = fws + 3 * NH;
  float* deginv = fws + 4 * NH;
  float* weff   = deginv + NND;
  float* pooled = weff + HD * HD;
  float* cnt    = pooled + NG * HD;
  int* degi   = (int*)(cnt + NG);
  int* rowptr = degi + NND;
  int* cursor = rowptr + (NND + 4);
  int* csrsrc = cursor + NND;

  hipMemsetAsync(degi, 0, NND * sizeof(int), stream);
  hipMemsetAsync(pooled, 0, (NG * HD + NG) * sizeof(float), stream);

  k_hist   <<<(NED + 255) / 256, 256, 0, stream>>>(edst, degi);
  k_scan   <<<1, 1024, 0, stream>>>(degi, rowptr, cursor, deginv);
  k_scatter<<<(NED + 255) / 256, 256, 0, stream>>>(esrc, edst, cursor, csrsrc);
  k_count  <<<(NND + 255) / 256, 256, 0, stream>>>(batch, cnt);
  k_weff   <<<(HD * HD + 255) / 256, 256, 0, stream>>>(Wint, weff);
  k_init   <<<(NND + 31) / 32, 256, 0, stream>>>(x, Win, bin, gin, bein,
                                                 Walt, balt, galt, bealt,
                                                 alpha, beta, h);
  for (int step = 0; step < 8; ++step) {
    for (int stage = 0; stage < 4; ++stage) {
      const float* ain = (stage == 0) ? h : y;
      k_spmm<<<(NND + 7) / 8, 256, 0, stream>>>(ain, rowptr, csrsrc, deginv, u);
      k_ode <<<(NND + 63) / 64, 256, 0, stream>>>(ain, u, Wself, Wmsg, bode,
                                                  h, kacc, (stage < 3) ? y : h, stage);
    }
  }
  k_interf<<<(NND + 63) / 64, 256, 0, stream>>>(h, weff, bint, gint, beint,
                                                alpha, beta, phase, y);
  k_out   <<<(NND + 63) / 64, 256, 0, stream>>>(y, Wout, bout, batch, pooled);
  k_final <<<(NG * HD + 255) / 256, 256, 0, stream>>>(pooled, cnt, out);
}

// Round 2
// 2743.482 us; speedup vs baseline: 1.7323x; 1.7323x over previous
//
#include <hip/hip_runtime.h>
#include <math.h>

#define NND 50000
#define NED 800000
#define HD  128
#define NG  64

typedef __attribute__((ext_vector_type(8))) short short8v;
typedef __attribute__((ext_vector_type(4))) float float4v;

__device__ __forceinline__ float gelu_t(float x) {
  const float c = 0.7978845608028654f;
  float t = tanhf(c * (x + 0.044715f * x * x * x));
  return 0.5f * x * (1.0f + t);
}

__device__ __forceinline__ unsigned short f2bf(float f) {
  unsigned int u = __float_as_uint(f);
  u += 0x7FFFu + ((u >> 16) & 1u);
  return (unsigned short)(u >> 16);
}
__device__ __forceinline__ float bflo(unsigned int u) { return __uint_as_float(u << 16); }
__device__ __forceinline__ float bfhi(unsigned int u) { return __uint_as_float(u & 0xFFFF0000u); }

// ---------------- CSR build ----------------
__global__ void k_hist(const int* __restrict__ dst, int* __restrict__ degi) {
  int e = blockIdx.x * 256 + threadIdx.x;
  if (e < NED) atomicAdd(&degi[dst[e]], 1);
}

__global__ void k_scan(const int* __restrict__ degi, int* __restrict__ rowptr,
                       int* __restrict__ cursor, float* __restrict__ deginv) {
  __shared__ int sh[1024];
  int tid = threadIdx.x;
  int running = 0;
  for (int base = 0; base < NND; base += 1024) {
    int idx = base + tid;
    int v = (idx < NND) ? degi[idx] : 0;
    sh[tid] = v;
    __syncthreads();
    for (int off = 1; off < 1024; off <<= 1) {
      int t = (tid >= off) ? sh[tid - off] : 0;
      __syncthreads();
      sh[tid] += t;
      __syncthreads();
    }
    int excl = running + sh[tid] - v;
    if (idx < NND) {
      rowptr[idx] = excl;
      cursor[idx] = excl;
      deginv[idx] = 1.0f / (float)max(v, 1);
    }
    int tot = sh[1023];
    __syncthreads();
    running += tot;
  }
  if (tid == 0) rowptr[NND] = running;
}

__global__ void k_scatter(const int* __restrict__ src, const int* __restrict__ dst,
                          int* __restrict__ cursor, int* __restrict__ csrsrc) {
  int e = blockIdx.x * 256 + threadIdx.x;
  if (e < NED) {
    int d = dst[e];
    int pos = atomicAdd(&cursor[d], 1);
    csrsrc[pos] = src[e];
  }
}

// batch is sorted -> per-graph counts by binary search (replaces atomic histogram)
__global__ void k_cnt(const int* __restrict__ batch, float* __restrict__ cnt) {
  int g = threadIdx.x;
  if (g >= NG) return;
  // upper_bound(batch, v)
  int lo, hi, ub_g, ub_gm1;
  lo = 0; hi = NND;
  while (lo < hi) { int mid = (lo + hi) >> 1; if (batch[mid] <= g) lo = mid + 1; else hi = mid; }
  ub_g = lo;
  if (g == 0) ub_gm1 = 0;
  else {
    lo = 0; hi = NND;
    int v = g - 1;
    while (lo < hi) { int mid = (lo + hi) >> 1; if (batch[mid] <= v) lo = mid + 1; else hi = mid; }
    ub_gm1 = lo;
  }
  cnt[g] = (float)(ub_g - ub_gm1);
}

__global__ void k_weff(const float* __restrict__ Wint, float* __restrict__ weff) {
  int i = blockIdx.x * 256 + threadIdx.x;
  if (i < HD * HD) weff[i] = Wint[i] + Wint[i + HD * HD];
}

// Bt[n][k] = bf16 of [Wself;Wmsg][k][n]  (n-major so MFMA B-frags are k-contiguous)
__global__ void k_prepB(const float* __restrict__ Wself, const float* __restrict__ Wmsg,
                        unsigned short* __restrict__ Bt) {
  int i = blockIdx.x * 256 + threadIdx.x;
  if (i < 128 * 256) {
    int n = i >> 8, k = i & 255;
    float w = (k < HD) ? Wself[k * HD + n] : Wmsg[(k - HD) * HD + n];
    Bt[i] = f2bf(w);
  }
}

// ---------------- init: h = w0*gelu(LN(x@Win+b)) + w1*gelu(LN(x@Walt+b)) ----------------
__global__ __launch_bounds__(256) void k_init(
    const float* __restrict__ x,
    const float* __restrict__ Win, const float* __restrict__ bin,
    const float* __restrict__ gin, const float* __restrict__ bein,
    const float* __restrict__ Walt, const float* __restrict__ balt,
    const float* __restrict__ galt, const float* __restrict__ bealt,
    const float* __restrict__ alphap, const float* __restrict__ betap,
    float* __restrict__ hdst, unsigned short* __restrict__ hbf)
{
  __shared__ float As[32][16];
  __shared__ float Bs[16][256];
  int tid = threadIdx.x;
  int lane = tid & 63;
  int ty = tid >> 6;
  int rowBase = blockIdx.x * 32;
  float acc[8][4];
#pragma unroll
  for (int i = 0; i < 8; ++i) { acc[i][0]=0.f; acc[i][1]=0.f; acc[i][2]=0.f; acc[i][3]=0.f; }

  for (int kc = 0; kc < 8; ++kc) {
    int k0 = kc * 16;
    if (tid < 128) {
      int r = tid >> 2, kq = (tid & 3) * 4;
      int row = rowBase + r; if (row >= NND) row = NND - 1;
      *(float4*)&As[r][kq] = *(const float4*)&x[(size_t)row * HD + k0 + kq];
    }
#pragma unroll
    for (int p = 0; p < 4; ++p) {
      int idx = p * 256 + tid;
      int kk = idx >> 6, cq = idx & 63;
      int col = cq * 4;
      int k = k0 + kk;
      const float* srcp = (col < HD) ? &Win[k * HD + col] : &Walt[k * HD + (col - HD)];
      *(float4*)&Bs[kk][col] = *(const float4*)srcp;
    }
    __syncthreads();
#pragma unroll
    for (int kq = 0; kq < 4; ++kq) {
      float4 b0 = *(float4*)&Bs[kq*4+0][lane*4];
      float4 b1 = *(float4*)&Bs[kq*4+1][lane*4];
      float4 b2 = *(float4*)&Bs[kq*4+2][lane*4];
      float4 b3 = *(float4*)&Bs[kq*4+3][lane*4];
#pragma unroll
      for (int i = 0; i < 8; ++i) {
        float4 a = *(float4*)&As[ty*8+i][kq*4];
        acc[i][0] = fmaf(a.x,b0.x,fmaf(a.y,b1.x,fmaf(a.z,b2.x,fmaf(a.w,b3.x,acc[i][0]))));
        acc[i][1] = fmaf(a.x,b0.y,fmaf(a.y,b1.y,fmaf(a.z,b2.y,fmaf(a.w,b3.y,acc[i][1]))));
        acc[i][2] = fmaf(a.x,b0.z,fmaf(a.y,b1.z,fmaf(a.z,b2.z,fmaf(a.w,b3.z,acc[i][2]))));
        acc[i][3] = fmaf(a.x,b0.w,fmaf(a.y,b1.w,fmaf(a.z,b2.w,fmaf(a.w,b3.w,acc[i][3]))));
      }
    }
    __syncthreads();
  }

  float al = alphap[0], bt = betap[0];
  float nrm = sqrtf(al*al + bt*bt);
  float w0 = fabsf(al) / nrm, w1 = fabsf(bt) / nrm;
  int path = lane >> 5;
  int cl = (lane & 31) * 4;
  const float* bvp = path ? balt : bin;
  const float* gp  = path ? galt : gin;
  const float* bep = path ? bealt : bein;
  float4 bv  = *(const float4*)&bvp[cl];
  float4 gv  = *(const float4*)&gp[cl];
  float4 bev = *(const float4*)&bep[cl];
#pragma unroll
  for (int i = 0; i < 8; ++i) {
    int row = rowBase + ty*8 + i;
    float z0 = acc[i][0]+bv.x, z1 = acc[i][1]+bv.y, z2 = acc[i][2]+bv.z, z3 = acc[i][3]+bv.w;
    float rsum = z0+z1+z2+z3;
    float rsq  = z0*z0+z1*z1+z2*z2+z3*z3;
#pragma unroll
    for (int m = 1; m < 32; m <<= 1) { rsum += __shfl_xor(rsum, m, 32); rsq += __shfl_xor(rsq, m, 32); }
    float mean = rsum * (1.0f/128.0f);
    float var  = rsq * (1.0f/128.0f) - mean*mean;
    float rs = rsqrtf(var + 1e-5f);
    float g0 = gelu_t((z0-mean)*rs*gv.x + bev.x);
    float g1 = gelu_t((z1-mean)*rs*gv.y + bev.y);
    float g2 = gelu_t((z2-mean)*rs*gv.z + bev.z);
    float g3 = gelu_t((z3-mean)*rs*gv.w + bev.w);
    float o0 = __shfl_xor(g0, 32, 64);
    float o1 = __shfl_xor(g1, 32, 64);
    float o2 = __shfl_xor(g2, 32, 64);
    float o3 = __shfl_xor(g3, 32, 64);
    if (row < NND && path == 0) {
      float h0 = fmaf(w0,g0,w1*o0);
      float h1 = fmaf(w0,g1,w1*o1);
      float h2 = fmaf(w0,g2,w1*o2);
      float h3 = fmaf(w0,g3,w1*o3);
      size_t off = (size_t)row * HD + cl;
      *(float4*)&hdst[off] = make_float4(h0, h1, h2, h3);
      hbf[off+0] = f2bf(h0); hbf[off+1] = f2bf(h1);
      hbf[off+2] = f2bf(h2); hbf[off+3] = f2bf(h3);
    }
  }
}

// ---------------- SpMM (bf16): u[i] = bf16( (sum_{j->i} yin[j]) * deginv[i] ) ----------------
__global__ __launch_bounds__(256) void k_spmm(
    const unsigned short* __restrict__ yin, const int* __restrict__ rowptr,
    const int* __restrict__ csrsrc, const float* __restrict__ deginv,
    unsigned short* __restrict__ u)
{
  int tid = threadIdx.x;
  int node = blockIdx.x * 16 + (tid >> 4);
  int l16 = tid & 15;
  if (node >= NND) return;
  int e0 = rowptr[node], e1 = rowptr[node + 1];
  float a0=0,a1=0,a2=0,a3=0,a4=0,a5=0,a6=0,a7=0;
  int e = e0;
  for (; e + 1 < e1; e += 2) {
    int s0 = csrsrc[e], s1 = csrsrc[e + 1];
    uint4 v0 = *(const uint4*)&yin[(size_t)s0 * HD + l16 * 8];
    uint4 v1 = *(const uint4*)&yin[(size_t)s1 * HD + l16 * 8];
    a0 += bflo(v0.x); a1 += bfhi(v0.x); a2 += bflo(v0.y); a3 += bfhi(v0.y);
    a4 += bflo(v0.z); a5 += bfhi(v0.z); a6 += bflo(v0.w); a7 += bfhi(v0.w);
    a0 += bflo(v1.x); a1 += bfhi(v1.x); a2 += bflo(v1.y); a3 += bfhi(v1.y);
    a4 += bflo(v1.z); a5 += bfhi(v1.z); a6 += bflo(v1.w); a7 += bfhi(v1.w);
  }
  if (e < e1) {
    int s0 = csrsrc[e];
    uint4 v0 = *(const uint4*)&yin[(size_t)s0 * HD + l16 * 8];
    a0 += bflo(v0.x); a1 += bfhi(v0.x); a2 += bflo(v0.y); a3 += bfhi(v0.y);
    a4 += bflo(v0.z); a5 += bfhi(v0.z); a6 += bflo(v0.w); a7 += bfhi(v0.w);
  }
  float di = deginv[node];
  uint4 o;
  o.x = (unsigned int)f2bf(a0 * di) | ((unsigned int)f2bf(a1 * di) << 16);
  o.y = (unsigned int)f2bf(a2 * di) | ((unsigned int)f2bf(a3 * di) << 16);
  o.z = (unsigned int)f2bf(a4 * di) | ((unsigned int)f2bf(a5 * di) << 16);
  o.w = (unsigned int)f2bf(a6 * di) | ((unsigned int)f2bf(a7 * di) << 16);
  *(uint4*)&u[(size_t)node * HD + l16 * 8] = o;
}

// ---------------- ODE: MFMA GEMM [ain|u] @ Bt^T + RK4 epilogue ----------------
__global__ __launch_bounds__(256) void k_ode(
    const unsigned short* __restrict__ ain, const unsigned short* __restrict__ ubf,
    const unsigned short* __restrict__ Bt, const float* __restrict__ bode,
    const float* __restrict__ h, float* __restrict__ hacc,
    float* __restrict__ hout, unsigned short* __restrict__ ybf,
    unsigned short* __restrict__ hbf, int stage)
{
  int tid = threadIdx.x;
  int wave = tid >> 6;
  int lane = tid & 63;
  int l15 = lane & 15;
  int lhi = lane >> 4;
  int rowBase = blockIdx.x * 64;
  int ncol0 = wave * 32;

  // B fragments: 2 n-tiles x 8 k-slices, k-contiguous from n-major Bt
  short8v bfr[2][8];
#pragma unroll
  for (int t = 0; t < 2; ++t) {
    int n = ncol0 + t * 16 + l15;
#pragma unroll
    for (int s = 0; s < 8; ++s) {
      bfr[t][s] = *(const short8v*)&Bt[n * 256 + s * 32 + lhi * 8];
    }
  }

  const float DT = 0.125f;
  float wk = (stage == 0 || stage == 3) ? DT / 6.0f : DT / 3.0f;
  float cy = (stage <= 1) ? 0.5f * DT : DT;
  float bo0 = bode[ncol0 + l15];
  float bo1 = bode[ncol0 + 16 + l15];

#pragma unroll
  for (int rt = 0; rt < 4; ++rt) {
    int mload = rowBase + rt * 16 + l15;
    if (mload >= NND) mload = NND - 1;
    short8v afr[8];
#pragma unroll
    for (int s = 0; s < 4; ++s)
      afr[s] = *(const short8v*)&ain[(size_t)mload * HD + s * 32 + lhi * 8];
#pragma unroll
    for (int s = 0; s < 4; ++s)
      afr[4 + s] = *(const short8v*)&ubf[(size_t)mload * HD + s * 32 + lhi * 8];

    float4v acc0 = {0.f, 0.f, 0.f, 0.f};
    float4v acc1 = {0.f, 0.f, 0.f, 0.f};
#pragma unroll
    for (int s = 0; s < 8; ++s) {
      acc0 = __builtin_amdgcn_mfma_f32_16x16x32_bf16(afr[s], bfr[0][s], acc0, 0, 0, 0);
      acc1 = __builtin_amdgcn_mfma_f32_16x16x32_bf16(afr[s], bfr[1][s], acc1, 0, 0, 0);
    }

#pragma unroll
    for (int t = 0; t < 2; ++t) {
      int n = ncol0 + t * 16 + l15;
      float bo = t ? bo1 : bo0;
#pragma unroll
      for (int r = 0; r < 4; ++r) {
        int m = rowBase + rt * 16 + lhi * 4 + r;
        if (m < NND) {
          size_t off = (size_t)m * HD + n;
          float av = t ? acc1[r] : acc0[r];
          float kv = tanhf(av + bo);
          if (stage == 0) {
            float hv = h[off];
            hacc[off] = hv + wk * kv;
            ybf[off] = f2bf(hv + cy * kv);
          } else if (stage < 3) {
            float hv = h[off];
            hacc[off] += wk * kv;
            ybf[off] = f2bf(hv + cy * kv);
          } else {
            float hn = hacc[off] + wk * kv;
            hout[off] = hn;
            hbf[off] = f2bf(hn);
          }
        }
      }
    }
  }
}

// ---------------- interference ----------------
__global__ __launch_bounds__(256) void k_interf(
    const float* __restrict__ h, const float* __restrict__ weff,
    const float* __restrict__ bint, const float* __restrict__ gint,
    const float* __restrict__ beint,
    const float* __restrict__ alphap, const float* __restrict__ betap,
    const float* __restrict__ phasep,
    float* __restrict__ h2out)
{
  __shared__ float As[64][16];
  __shared__ float Bs[16][128];
  int tid = threadIdx.x;
  int tx = tid & 31, ty = tid >> 5;
  int rowBase = blockIdx.x * 64;
  float acc[8][4];
#pragma unroll
  for (int i = 0; i < 8; ++i) { acc[i][0]=0.f; acc[i][1]=0.f; acc[i][2]=0.f; acc[i][3]=0.f; }

  for (int kc = 0; kc < 8; ++kc) {
    int k0 = kc * 16;
    {
      int r = tid >> 2, kq = (tid & 3) * 4;
      int row = rowBase + r; if (row >= NND) row = NND - 1;
      *(float4*)&As[r][kq] = *(const float4*)&h[(size_t)row * HD + k0 + kq];
    }
#pragma unroll
    for (int j = 0; j < 2; ++j) {
      int kk = (tid >> 5) + j * 8;
      int n = (tid & 31) * 4;
      *(float4*)&Bs[kk][n] = *(const float4*)&weff[(k0 + kk) * HD + n];
    }
    __syncthreads();
#pragma unroll
    for (int kq = 0; kq < 4; ++kq) {
      float4 b0 = *(float4*)&Bs[kq*4+0][tx*4];
      float4 b1 = *(float4*)&Bs[kq*4+1][tx*4];
      float4 b2 = *(float4*)&Bs[kq*4+2][tx*4];
      float4 b3 = *(float4*)&Bs[kq*4+3][tx*4];
#pragma unroll
      for (int i = 0; i < 8; ++i) {
        float4 a = *(float4*)&As[ty*8+i][kq*4];
        acc[i][0] = fmaf(a.x,b0.x,fmaf(a.y,b1.x,fmaf(a.z,b2.x,fmaf(a.w,b3.x,acc[i][0]))));
        acc[i][1] = fmaf(a.x,b0.y,fmaf(a.y,b1.y,fmaf(a.z,b2.y,fmaf(a.w,b3.y,acc[i][1]))));
        acc[i][2] = fmaf(a.x,b0.z,fmaf(a.y,b1.z,fmaf(a.z,b2.z,fmaf(a.w,b3.z,acc[i][2]))));
        acc[i][3] = fmaf(a.x,b0.w,fmaf(a.y,b1.w,fmaf(a.z,b2.w,fmaf(a.w,b3.w,acc[i][3]))));
      }
    }
    __syncthreads();
  }

  float al = alphap[0], bt = betap[0], ph = phasep[0];
  float n2 = al*al + bt*bt;
  float p0 = (al*al) / n2, p1 = (bt*bt) / n2;
  float interf = 2.0f * sqrtf(p0 * p1) * cosf(ph);
  float gate = (fabsf(interf) > 0.01f) ? interf : 0.0f;
  float cscale = (p0 > p1) ? 1.0f : cosf(ph);

  int c0 = tx * 4;
  float4 bi  = *(const float4*)&bint[c0];
  float4 gv  = *(const float4*)&gint[c0];
  float4 bev = *(const float4*)&beint[c0];
#pragma unroll
  for (int i = 0; i < 8; ++i) {
    int row = rowBase + ty*8 + i;
    float z0 = acc[i][0]+bi.x, z1 = acc[i][1]+bi.y, z2 = acc[i][2]+bi.z, z3 = acc[i][3]+bi.w;
    float rsum = z0+z1+z2+z3;
    float rsq  = z0*z0+z1*z1+z2*z2+z3*z3;
#pragma unroll
    for (int m = 1; m < 32; m <<= 1) { rsum += __shfl_xor(rsum, m, 32); rsq += __shfl_xor(rsq, m, 32); }
    float mean = rsum * (1.0f/128.0f);
    float var  = rsq * (1.0f/128.0f) - mean*mean;
    float rs = rsqrtf(var + 1e-5f);
    float t0 = tanhf((z0-mean)*rs*gv.x + bev.x);
    float t1 = tanhf((z1-mean)*rs*gv.y + bev.y);
    float t2 = tanhf((z2-mean)*rs*gv.z + bev.z);
    float t3 = tanhf((z3-mean)*rs*gv.w + bev.w);
    if (row < NND) {
      size_t off = (size_t)row * HD + c0;
      float4 hv = *(const float4*)&h[off];
      float4 o = make_float4((hv.x + gate*t0) * cscale,
                             (hv.y + gate*t1) * cscale,
                             (hv.z + gate*t2) * cscale,
                             (hv.w + gate*t3) * cscale);
      *(float4*)&h2out[off] = o;
    }
  }
}

// ---------------- output GEMM + pooled atomic accumulation ----------------
__global__ __launch_bounds__(256) void k_out(
    const float* __restrict__ h2, const float* __restrict__ Wout,
    const float* __restrict__ bout, const int* __restrict__ batch,
    float* __restrict__ pooled)
{
  __shared__ float As[64][16];
  __shared__ float Bs[16][128];
  int tid = threadIdx.x;
  int tx = tid & 31, ty = tid >> 5;
  int rowBase = blockIdx.x * 64;
  float acc[8][4];
#pragma unroll
  for (int i = 0; i < 8; ++i) { acc[i][0]=0.f; acc[i][1]=0.f; acc[i][2]=0.f; acc[i][3]=0.f; }

  for (int kc = 0; kc < 8; ++kc) {
    int k0 = kc * 16;
    {
      int r = tid >> 2, kq = (tid & 3) * 4;
      int row = rowBase + r; if (row >= NND) row = NND - 1;
      *(float4*)&As[r][kq] = *(const float4*)&h2[(size_t)row * HD + k0 + kq];
    }
#pragma unroll
    for (int j = 0; j < 2; ++j) {
      int kk = (tid >> 5) + j * 8;
      int n = (tid & 31) * 4;
      *(float4*)&Bs[kk][n] = *(const float4*)&Wout[(k0 + kk) * HD + n];
    }
    __syncthreads();
#pragma unroll
    for (int kq = 0; kq < 4; ++kq) {
      float4 b0 = *(float4*)&Bs[kq*4+0][tx*4];
      float4 b1 = *(float4*)&Bs[kq*4+1][tx*4];
      float4 b2 = *(float4*)&Bs[kq*4+2][tx*4];
      float4 b3 = *(float4*)&Bs[kq*4+3][tx*4];
#pragma unroll
      for (int i = 0; i < 8; ++i) {
        float4 a = *(float4*)&As[ty*8+i][kq*4];
        acc[i][0] = fmaf(a.x,b0.x,fmaf(a.y,b1.x,fmaf(a.z,b2.x,fmaf(a.w,b3.x,acc[i][0]))));
        acc[i][1] = fmaf(a.x,b0.y,fmaf(a.y,b1.y,fmaf(a.z,b2.y,fmaf(a.w,b3.y,acc[i][1]))));
        acc[i][2] = fmaf(a.x,b0.z,fmaf(a.y,b1.z,fmaf(a.z,b2.z,fmaf(a.w,b3.z,acc[i][2]))));
        acc[i][3] = fmaf(a.x,b0.w,fmaf(a.y,b1.w,fmaf(a.z,b2.w,fmaf(a.w,b3.w,acc[i][3]))));
      }
    }
    __syncthreads();
  }

  int c0 = tx * 4;
  float4 bo = *(const float4*)&bout[c0];
  int prevg = -1;
  float r0 = 0.f, r1 = 0.f, r2 = 0.f, r3 = 0.f;
#pragma unroll
  for (int i = 0; i < 8; ++i) {
    int row = rowBase + ty*8 + i;
    if (row >= NND) break;
    int g = batch[row];
    float v0 = acc[i][0] + bo.x;
    float v1 = acc[i][1] + bo.y;
    float v2 = acc[i][2] + bo.z;
    float v3 = acc[i][3] + bo.w;
    if (g != prevg) {
      if (prevg >= 0) {
        atomicAdd(&pooled[prevg*HD + c0 + 0], r0);
        atomicAdd(&pooled[prevg*HD + c0 + 1], r1);
        atomicAdd(&pooled[prevg*HD + c0 + 2], r2);
        atomicAdd(&pooled[prevg*HD + c0 + 3], r3);
      }
      prevg = g; r0 = v0; r1 = v1; r2 = v2; r3 = v3;
    } else {
      r0 += v0; r1 += v1; r2 += v2; r3 += v3;
    }
  }
  if (prevg >= 0) {
    atomicAdd(&pooled[prevg*HD + c0 + 0], r0);
    atomicAdd(&pooled[prevg*HD + c0 + 1], r1);
    atomicAdd(&pooled[prevg*HD + c0 + 2], r2);
    atomicAdd(&pooled[prevg*HD + c0 + 3], r3);
  }
}

__global__ void k_final(const float* __restrict__ pooled, const float* __restrict__ cnt,
                        float* __restrict__ out) {
  int i = blockIdx.x * 256 + threadIdx.x;
  if (i < NG * HD) out[i] = pooled[i] / fmaxf(cnt[i >> 7], 1.0f);
}

extern "C" void kernel_launch(void* const* d_in, const int* in_sizes, int n_in,
                              void* d_out, int out_size, void* d_ws, size_t ws_size,
                              hipStream_t stream) {
  (void)in_sizes; (void)n_in; (void)out_size; (void)ws_size;
  const float* x     = (const float*)d_in[0];
  const int*   ei    = (const int*)d_in[1];
  const int*   batch = (const int*)d_in[2];
  const float* alpha = (const float*)d_in[3];
  const float* beta  = (const float*)d_in[4];
  const float* phase = (const float*)d_in[5];
  const float* Win   = (const float*)d_in[6];
  const float* bin   = (const float*)d_in[7];
  const float* gin   = (const float*)d_in[8];
  const float* bein  = (const float*)d_in[9];
  const float* Walt  = (const float*)d_in[10];
  const float* balt  = (const float*)d_in[11];
  const float* galt  = (const float*)d_in[12];
  const float* bealt = (const float*)d_in[13];
  const float* Wself = (const float*)d_in[14];
  const float* Wmsg  = (const float*)d_in[15];
  const float* bode  = (const float*)d_in[16];
  const float* Wint  = (const float*)d_in[17];
  const float* bint  = (const float*)d_in[18];
  const float* gint  = (const float*)d_in[19];
  const float* beint = (const float*)d_in[20];
  const float* Wout  = (const float*)d_in[21];
  const float* bout  = (const float*)d_in[22];
  float* out = (float*)d_out;

  const int* esrc = ei;
  const int* edst = ei + NED;

  size_t NH = (size_t)NND * HD;   // 6,400,000
  float* h      = (float*)d_ws;
  float* hacc   = h + NH;
  float* deginv = hacc + NH;
  float* weff   = deginv + NND;
  float* pooled = weff + HD * HD;
  float* cnt    = pooled + NG * HD;
  unsigned short* hbf = (unsigned short*)(cnt + NG);
  unsigned short* ybf = hbf + NH;
  unsigned short* ubf = ybf + NH;
  unsigned short* Bt  = ubf + NH;          // 128*256
  int* degi   = (int*)(Bt + 128 * 256);
  int* rowptr = degi + NND;
  int* cursor = rowptr + (NND + 4);
  int* csrsrc = cursor + NND;

  hipMemsetAsync(degi, 0, NND * sizeof(int), stream);
  hipMemsetAsync(pooled, 0, NG * HD * sizeof(float), stream);

  k_hist   <<<(NED + 255) / 256, 256, 0, stream>>>(edst, degi);
  k_scan   <<<1, 1024, 0, stream>>>(degi, rowptr, cursor, deginv);
  k_scatter<<<(NED + 255) / 256, 256, 0, stream>>>(esrc, edst, cursor, csrsrc);
  k_cnt    <<<1, 64, 0, stream>>>(batch, cnt);
  k_weff   <<<(HD * HD + 255) / 256, 256, 0, stream>>>(Wint, weff);
  k_prepB  <<<128, 256, 0, stream>>>(Wself, Wmsg, Bt);
  k_init   <<<(NND + 31) / 32, 256, 0, stream>>>(x, Win, bin, gin, bein,
                                                 Walt, balt, galt, bealt,
                                                 alpha, beta, h, hbf);
  for (int step = 0; step < 8; ++step) {
    for (int stage = 0; stage < 4; ++stage) {
      const unsigned short* ainbf = (stage == 0) ? hbf : ybf;
      k_spmm<<<(NND + 15) / 16, 256, 0, stream>>>(ainbf, rowptr, csrsrc, deginv, ubf);
      k_ode <<<(NND + 63) / 64, 256, 0, stream>>>(ainbf, ubf, Bt, bode,
                                                  h, hacc, h, ybf, hbf, stage);
    }
  }
  k_interf<<<(NND + 63) / 64, 256, 0, stream>>>(h, weff, bint, gint, beint,
                                                alpha, beta, phase, hacc);
  k_out   <<<(NND + 63) / 64, 256, 0, stream>>>(hacc, Wout, bout, batch, pooled);
  k_final <<<(NG * HD + 255) / 256, 256, 0, stream>>>(pooled, cnt, out);
}

// Round 3
// 2356.965 us; speedup vs baseline: 2.0164x; 1.1640x over previous
//
#include <hip/hip_runtime.h>
#include <math.h>

#define NND 50000
#define NED 800000
#define HD  128
#define NG  64

typedef __attribute__((ext_vector_type(8))) short short8v;
typedef __attribute__((ext_vector_type(4))) float float4v;

__device__ __forceinline__ float gelu_t(float x) {
  const float c = 0.7978845608028654f;
  float t = tanhf(c * (x + 0.044715f * x * x * x));
  return 0.5f * x * (1.0f + t);
}

__device__ __forceinline__ unsigned short f2bf(float f) {
  unsigned int u = __float_as_uint(f);
  u += 0x7FFFu + ((u >> 16) & 1u);
  return (unsigned short)(u >> 16);
}
__device__ __forceinline__ float bf2f(unsigned short s) {
  return __uint_as_float(((unsigned int)s) << 16);
}
__device__ __forceinline__ float bflo(unsigned int u) { return __uint_as_float(u << 16); }
__device__ __forceinline__ float bfhi(unsigned int u) { return __uint_as_float(u & 0xFFFF0000u); }

// ---------------- CSR build ----------------
__global__ void k_hist(const int* __restrict__ dst, int* __restrict__ degi) {
  int e = blockIdx.x * 256 + threadIdx.x;
  if (e < NED) atomicAdd(&degi[dst[e]], 1);
}

// wave-shuffle scan, 1 block x 1024 threads
__global__ __launch_bounds__(1024) void k_scan(
    const int* __restrict__ degi, int* __restrict__ rowptr,
    int* __restrict__ cursor, float* __restrict__ deginv) {
  __shared__ int wsum[16];
  int tid = threadIdx.x;
  int lane = tid & 63;
  int wid = tid >> 6;
  int running = 0;
  for (int base = 0; base < NND; base += 1024) {
    int idx = base + tid;
    int v = (idx < NND) ? degi[idx] : 0;
    int s = v;
#pragma unroll
    for (int o = 1; o < 64; o <<= 1) {
      int t = __shfl_up(s, o, 64);
      if (lane >= o) s += t;
    }
    if (lane == 63) wsum[wid] = s;
    __syncthreads();
    if (wid == 0) {
      int ws = (lane < 16) ? wsum[lane] : 0;
#pragma unroll
      for (int o = 1; o < 16; o <<= 1) {
        int t = __shfl_up(ws, o, 64);
        if (lane >= o) ws += t;
      }
      if (lane < 16) wsum[lane] = ws;
    }
    __syncthreads();
    int woff = wid ? wsum[wid - 1] : 0;
    int excl = running + woff + s - v;
    if (idx < NND) {
      rowptr[idx] = excl;
      cursor[idx] = excl;
      deginv[idx] = 1.0f / (float)max(v, 1);
    }
    int tot = wsum[15];
    __syncthreads();
    running += tot;
  }
  if (tid == 0) rowptr[NND] = running;
}

__global__ void k_scatter(const int* __restrict__ src, const int* __restrict__ dst,
                          int* __restrict__ cursor, int* __restrict__ csrsrc) {
  int e = blockIdx.x * 256 + threadIdx.x;
  if (e < NED) {
    int d = dst[e];
    int pos = atomicAdd(&cursor[d], 1);
    csrsrc[pos] = src[e];
  }
}

// batch is sorted -> per-graph counts by binary search
__global__ void k_cnt(const int* __restrict__ batch, float* __restrict__ cnt) {
  int g = threadIdx.x;
  if (g >= NG) return;
  int lo, hi, ub_g, ub_gm1;
  lo = 0; hi = NND;
  while (lo < hi) { int mid = (lo + hi) >> 1; if (batch[mid] <= g) lo = mid + 1; else hi = mid; }
  ub_g = lo;
  if (g == 0) ub_gm1 = 0;
  else {
    lo = 0; hi = NND;
    int v = g - 1;
    while (lo < hi) { int mid = (lo + hi) >> 1; if (batch[mid] <= v) lo = mid + 1; else hi = mid; }
    ub_gm1 = lo;
  }
  cnt[g] = (float)(ub_g - ub_gm1);
}

__global__ void k_weff(const float* __restrict__ Wint, float* __restrict__ weff) {
  int i = blockIdx.x * 256 + threadIdx.x;
  if (i < HD * HD) weff[i] = Wint[i] + Wint[i + HD * HD];
}

// Bt[n][k] = bf16 of [Wself;Wmsg][k][n]
__global__ void k_prepB(const float* __restrict__ Wself, const float* __restrict__ Wmsg,
                        unsigned short* __restrict__ Bt) {
  int i = blockIdx.x * 256 + threadIdx.x;
  if (i < 128 * 256) {
    int n = i >> 8, k = i & 255;
    float w = (k < HD) ? Wself[k * HD + n] : Wmsg[(k - HD) * HD + n];
    Bt[i] = f2bf(w);
  }
}

// ---------------- init ----------------
__global__ __launch_bounds__(256) void k_init(
    const float* __restrict__ x,
    const float* __restrict__ Win, const float* __restrict__ bin,
    const float* __restrict__ gin, const float* __restrict__ bein,
    const float* __restrict__ Walt, const float* __restrict__ balt,
    const float* __restrict__ galt, const float* __restrict__ bealt,
    const float* __restrict__ alphap, const float* __restrict__ betap,
    float* __restrict__ hdst, unsigned short* __restrict__ hbf)
{
  __shared__ float As[32][16];
  __shared__ float Bs[16][256];
  int tid = threadIdx.x;
  int lane = tid & 63;
  int ty = tid >> 6;
  int rowBase = blockIdx.x * 32;
  float acc[8][4];
#pragma unroll
  for (int i = 0; i < 8; ++i) { acc[i][0]=0.f; acc[i][1]=0.f; acc[i][2]=0.f; acc[i][3]=0.f; }

  for (int kc = 0; kc < 8; ++kc) {
    int k0 = kc * 16;
    if (tid < 128) {
      int r = tid >> 2, kq = (tid & 3) * 4;
      int row = rowBase + r; if (row >= NND) row = NND - 1;
      *(float4*)&As[r][kq] = *(const float4*)&x[(size_t)row * HD + k0 + kq];
    }
#pragma unroll
    for (int p = 0; p < 4; ++p) {
      int idx = p * 256 + tid;
      int kk = idx >> 6, cq = idx & 63;
      int col = cq * 4;
      int k = k0 + kk;
      const float* srcp = (col < HD) ? &Win[k * HD + col] : &Walt[k * HD + (col - HD)];
      *(float4*)&Bs[kk][col] = *(const float4*)srcp;
    }
    __syncthreads();
#pragma unroll
    for (int kq = 0; kq < 4; ++kq) {
      float4 b0 = *(float4*)&Bs[kq*4+0][lane*4];
      float4 b1 = *(float4*)&Bs[kq*4+1][lane*4];
      float4 b2 = *(float4*)&Bs[kq*4+2][lane*4];
      float4 b3 = *(float4*)&Bs[kq*4+3][lane*4];
#pragma unroll
      for (int i = 0; i < 8; ++i) {
        float4 a = *(float4*)&As[ty*8+i][kq*4];
        acc[i][0] = fmaf(a.x,b0.x,fmaf(a.y,b1.x,fmaf(a.z,b2.x,fmaf(a.w,b3.x,acc[i][0]))));
        acc[i][1] = fmaf(a.x,b0.y,fmaf(a.y,b1.y,fmaf(a.z,b2.y,fmaf(a.w,b3.y,acc[i][1]))));
        acc[i][2] = fmaf(a.x,b0.z,fmaf(a.y,b1.z,fmaf(a.z,b2.z,fmaf(a.w,b3.z,acc[i][2]))));
        acc[i][3] = fmaf(a.x,b0.w,fmaf(a.y,b1.w,fmaf(a.z,b2.w,fmaf(a.w,b3.w,acc[i][3]))));
      }
    }
    __syncthreads();
  }

  float al = alphap[0], bt = betap[0];
  float nrm = sqrtf(al*al + bt*bt);
  float w0 = fabsf(al) / nrm, w1 = fabsf(bt) / nrm;
  int path = lane >> 5;
  int cl = (lane & 31) * 4;
  const float* bvp = path ? balt : bin;
  const float* gp  = path ? galt : gin;
  const float* bep = path ? bealt : bein;
  float4 bv  = *(const float4*)&bvp[cl];
  float4 gv  = *(const float4*)&gp[cl];
  float4 bev = *(const float4*)&bep[cl];
#pragma unroll
  for (int i = 0; i < 8; ++i) {
    int row = rowBase + ty*8 + i;
    float z0 = acc[i][0]+bv.x, z1 = acc[i][1]+bv.y, z2 = acc[i][2]+bv.z, z3 = acc[i][3]+bv.w;
    float rsum = z0+z1+z2+z3;
    float rsq  = z0*z0+z1*z1+z2*z2+z3*z3;
#pragma unroll
    for (int m = 1; m < 32; m <<= 1) { rsum += __shfl_xor(rsum, m, 32); rsq += __shfl_xor(rsq, m, 32); }
    float mean = rsum * (1.0f/128.0f);
    float var  = rsq * (1.0f/128.0f) - mean*mean;
    float rs = rsqrtf(var + 1e-5f);
    float g0 = gelu_t((z0-mean)*rs*gv.x + bev.x);
    float g1 = gelu_t((z1-mean)*rs*gv.y + bev.y);
    float g2 = gelu_t((z2-mean)*rs*gv.z + bev.z);
    float g3 = gelu_t((z3-mean)*rs*gv.w + bev.w);
    float o0 = __shfl_xor(g0, 32, 64);
    float o1 = __shfl_xor(g1, 32, 64);
    float o2 = __shfl_xor(g2, 32, 64);
    float o3 = __shfl_xor(g3, 32, 64);
    if (row < NND && path == 0) {
      float h0 = fmaf(w0,g0,w1*o0);
      float h1 = fmaf(w0,g1,w1*o1);
      float h2 = fmaf(w0,g2,w1*o2);
      float h3 = fmaf(w0,g3,w1*o3);
      size_t off = (size_t)row * HD + cl;
      *(float4*)&hdst[off] = make_float4(h0, h1, h2, h3);
      hbf[off+0] = f2bf(h0); hbf[off+1] = f2bf(h1);
      hbf[off+2] = f2bf(h2); hbf[off+3] = f2bf(h3);
    }
  }
}

// ---------------- fused: SpMM(gather->LDS) + MFMA GEMM + RK4 epilogue ----------------
__global__ __launch_bounds__(256) void k_fused(
    const unsigned short* __restrict__ ain, const int* __restrict__ rowptr,
    const int* __restrict__ csrsrc, const float* __restrict__ deginv,
    const unsigned short* __restrict__ Bt, const float* __restrict__ bode,
    const float* __restrict__ h, float* __restrict__ hacc,
    float* __restrict__ hout, unsigned short* __restrict__ ybf,
    unsigned short* __restrict__ hbf, int stage)
{
  __shared__ unsigned char u_lds[64 * 256];   // 64 rows x 128 bf16, XOR-swizzled
  int tid = threadIdx.x;
  int wave = tid >> 6;
  int lane = tid & 63;
  int l15 = lane & 15;
  int lhi = lane >> 4;
  int rowBase = blockIdx.x * 64;
  int ncol0 = wave * 32;

  // ---- phase 1: gather neighbor sums for this block's 64 rows ----
  {
    int l16 = tid & 15;
    int grp = tid >> 4;   // 0..15
#pragma unroll
    for (int g = 0; g < 4; ++g) {
      int nloc = g * 16 + grp;
      int node = rowBase + nloc;
      if (node < NND) {
        int e0 = rowptr[node], e1 = rowptr[node + 1];
        float a0=0,a1=0,a2=0,a3=0,a4=0,a5=0,a6=0,a7=0;
        int e = e0;
        for (; e + 3 < e1; e += 4) {
          int s0 = csrsrc[e], s1 = csrsrc[e+1], s2 = csrsrc[e+2], s3 = csrsrc[e+3];
          uint4 v0 = *(const uint4*)&ain[(size_t)s0 * HD + l16 * 8];
          uint4 v1 = *(const uint4*)&ain[(size_t)s1 * HD + l16 * 8];
          uint4 v2 = *(const uint4*)&ain[(size_t)s2 * HD + l16 * 8];
          uint4 v3 = *(const uint4*)&ain[(size_t)s3 * HD + l16 * 8];
          a0 += bflo(v0.x)+bflo(v1.x)+bflo(v2.x)+bflo(v3.x);
          a1 += bfhi(v0.x)+bfhi(v1.x)+bfhi(v2.x)+bfhi(v3.x);
          a2 += bflo(v0.y)+bflo(v1.y)+bflo(v2.y)+bflo(v3.y);
          a3 += bfhi(v0.y)+bfhi(v1.y)+bfhi(v2.y)+bfhi(v3.y);
          a4 += bflo(v0.z)+bflo(v1.z)+bflo(v2.z)+bflo(v3.z);
          a5 += bfhi(v0.z)+bfhi(v1.z)+bfhi(v2.z)+bfhi(v3.z);
          a6 += bflo(v0.w)+bflo(v1.w)+bflo(v2.w)+bflo(v3.w);
          a7 += bfhi(v0.w)+bfhi(v1.w)+bfhi(v2.w)+bfhi(v3.w);
        }
        for (; e < e1; ++e) {
          int s0 = csrsrc[e];
          uint4 v0 = *(const uint4*)&ain[(size_t)s0 * HD + l16 * 8];
          a0 += bflo(v0.x); a1 += bfhi(v0.x); a2 += bflo(v0.y); a3 += bfhi(v0.y);
          a4 += bflo(v0.z); a5 += bfhi(v0.z); a6 += bflo(v0.w); a7 += bfhi(v0.w);
        }
        float di = deginv[node];
        uint4 o;
        o.x = (unsigned int)f2bf(a0*di) | ((unsigned int)f2bf(a1*di) << 16);
        o.y = (unsigned int)f2bf(a2*di) | ((unsigned int)f2bf(a3*di) << 16);
        o.z = (unsigned int)f2bf(a4*di) | ((unsigned int)f2bf(a5*di) << 16);
        o.w = (unsigned int)f2bf(a6*di) | ((unsigned int)f2bf(a7*di) << 16);
        unsigned int boff = (unsigned int)nloc * 256u + (((unsigned int)l16 * 16u) ^ (((unsigned int)nloc & 7u) << 4));
        *(uint4*)&u_lds[boff] = o;
      }
    }
  }

  // ---- B fragments ----
  short8v bfr[2][8];
#pragma unroll
  for (int t = 0; t < 2; ++t) {
    int n = ncol0 + t * 16 + l15;
#pragma unroll
    for (int s = 0; s < 8; ++s) {
      bfr[t][s] = *(const short8v*)&Bt[n * 256 + s * 32 + lhi * 8];
    }
  }

  const float DT = 0.125f;
  float wk = (stage == 0 || stage == 3) ? DT / 6.0f : DT / 3.0f;
  float cy = (stage <= 1) ? 0.5f * DT : DT;
  float bo0 = bode[ncol0 + l15];
  float bo1 = bode[ncol0 + 16 + l15];

  __syncthreads();

  // ---- phase 2: MFMA + epilogue ----
#pragma unroll
  for (int rt = 0; rt < 4; ++rt) {
    int rloc = rt * 16 + l15;
    int mload = rowBase + rloc;
    if (mload >= NND) mload = NND - 1;
    short8v afr[8];
#pragma unroll
    for (int s = 0; s < 4; ++s)
      afr[s] = *(const short8v*)&ain[(size_t)mload * HD + s * 32 + lhi * 8];
#pragma unroll
    for (int s = 0; s < 4; ++s) {
      unsigned int boff = (unsigned int)rloc * 256u +
        ((((unsigned int)s * 64u) + ((unsigned int)lhi * 16u)) ^ (((unsigned int)rloc & 7u) << 4));
      afr[4 + s] = *(const short8v*)&u_lds[boff];
    }

    float4v acc0 = {0.f, 0.f, 0.f, 0.f};
    float4v acc1 = {0.f, 0.f, 0.f, 0.f};
#pragma unroll
    for (int s = 0; s < 8; ++s) {
      acc0 = __builtin_amdgcn_mfma_f32_16x16x32_bf16(afr[s], bfr[0][s], acc0, 0, 0, 0);
      acc1 = __builtin_amdgcn_mfma_f32_16x16x32_bf16(afr[s], bfr[1][s], acc1, 0, 0, 0);
    }

#pragma unroll
    for (int t = 0; t < 2; ++t) {
      int n = ncol0 + t * 16 + l15;
      float bo = t ? bo1 : bo0;
#pragma unroll
      for (int r = 0; r < 4; ++r) {
        int m = rowBase + rt * 16 + lhi * 4 + r;
        if (m < NND) {
          size_t off = (size_t)m * HD + n;
          float av = t ? acc1[r] : acc0[r];
          float kv = tanhf(av + bo);
          if (stage == 0) {
            float hv = h[off];
            hacc[off] = hv + wk * kv;
            ybf[off] = f2bf(hv + cy * kv);
          } else if (stage < 3) {
            hacc[off] += wk * kv;
            ybf[off] = f2bf(bf2f(hbf[off]) + cy * kv);
          } else {
            float hn = hacc[off] + wk * kv;
            hout[off] = hn;
            hbf[off] = f2bf(hn);
          }
        }
      }
    }
  }
}

// ---------------- interference ----------------
__global__ __launch_bounds__(256) void k_interf(
    const float* __restrict__ h, const float* __restrict__ weff,
    const float* __restrict__ bint, const float* __restrict__ gint,
    const float* __restrict__ beint,
    const float* __restrict__ alphap, const float* __restrict__ betap,
    const float* __restrict__ phasep,
    float* __restrict__ h2out)
{
  __shared__ float As[64][16];
  __shared__ float Bs[16][128];
  int tid = threadIdx.x;
  int tx = tid & 31, ty = tid >> 5;
  int rowBase = blockIdx.x * 64;
  float acc[8][4];
#pragma unroll
  for (int i = 0; i < 8; ++i) { acc[i][0]=0.f; acc[i][1]=0.f; acc[i][2]=0.f; acc[i][3]=0.f; }

  for (int kc = 0; kc < 8; ++kc) {
    int k0 = kc * 16;
    {
      int r = tid >> 2, kq = (tid & 3) * 4;
      int row = rowBase + r; if (row >= NND) row = NND - 1;
      *(float4*)&As[r][kq] = *(const float4*)&h[(size_t)row * HD + k0 + kq];
    }
#pragma unroll
    for (int j = 0; j < 2; ++j) {
      int kk = (tid >> 5) + j * 8;
      int n = (tid & 31) * 4;
      *(float4*)&Bs[kk][n] = *(const float4*)&weff[(k0 + kk) * HD + n];
    }
    __syncthreads();
#pragma unroll
    for (int kq = 0; kq < 4; ++kq) {
      float4 b0 = *(float4*)&Bs[kq*4+0][tx*4];
      float4 b1 = *(float4*)&Bs[kq*4+1][tx*4];
      float4 b2 = *(float4*)&Bs[kq*4+2][tx*4];
      float4 b3 = *(float4*)&Bs[kq*4+3][tx*4];
#pragma unroll
      for (int i = 0; i < 8; ++i) {
        float4 a = *(float4*)&As[ty*8+i][kq*4];
        acc[i][0] = fmaf(a.x,b0.x,fmaf(a.y,b1.x,fmaf(a.z,b2.x,fmaf(a.w,b3.x,acc[i][0]))));
        acc[i][1] = fmaf(a.x,b0.y,fmaf(a.y,b1.y,fmaf(a.z,b2.y,fmaf(a.w,b3.y,acc[i][1]))));
        acc[i][2] = fmaf(a.x,b0.z,fmaf(a.y,b1.z,fmaf(a.z,b2.z,fmaf(a.w,b3.z,acc[i][2]))));
        acc[i][3] = fmaf(a.x,b0.w,fmaf(a.y,b1.w,fmaf(a.z,b2.w,fmaf(a.w,b3.w,acc[i][3]))));
      }
    }
    __syncthreads();
  }

  float al = alphap[0], bt = betap[0], ph = phasep[0];
  float n2 = al*al + bt*bt;
  float p0 = (al*al) / n2, p1 = (bt*bt) / n2;
  float interf = 2.0f * sqrtf(p0 * p1) * cosf(ph);
  float gate = (fabsf(interf) > 0.01f) ? interf : 0.0f;
  float cscale = (p0 > p1) ? 1.0f : cosf(ph);

  int c0 = tx * 4;
  float4 bi  = *(const float4*)&bint[c0];
  float4 gv  = *(const float4*)&gint[c0];
  float4 bev = *(const float4*)&beint[c0];
#pragma unroll
  for (int i = 0; i < 8; ++i) {
    int row = rowBase + ty*8 + i;
    float z0 = acc[i][0]+bi.x, z1 = acc[i][1]+bi.y, z2 = acc[i][2]+bi.z, z3 = acc[i][3]+bi.w;
    float rsum = z0+z1+z2+z3;
    float rsq  = z0*z0+z1*z1+z2*z2+z3*z3;
#pragma unroll
    for (int m = 1; m < 32; m <<= 1) { rsum += __shfl_xor(rsum, m, 32); rsq += __shfl_xor(rsq, m, 32); }
    float mean = rsum * (1.0f/128.0f);
    float var  = rsq * (1.0f/128.0f) - mean*mean;
    float rs = rsqrtf(var + 1e-5f);
    float t0 = tanhf((z0-mean)*rs*gv.x + bev.x);
    float t1 = tanhf((z1-mean)*rs*gv.y + bev.y);
    float t2 = tanhf((z2-mean)*rs*gv.z + bev.z);
    float t3 = tanhf((z3-mean)*rs*gv.w + bev.w);
    if (row < NND) {
      size_t off = (size_t)row * HD + c0;
      float4 hv = *(const float4*)&h[off];
      float4 o = make_float4((hv.x + gate*t0) * cscale,
                             (hv.y + gate*t1) * cscale,
                             (hv.z + gate*t2) * cscale,
                             (hv.w + gate*t3) * cscale);
      *(float4*)&h2out[off] = o;
    }
  }
}

// ---------------- output GEMM + pooled atomic accumulation ----------------
__global__ __launch_bounds__(256) void k_out(
    const float* __restrict__ h2, const float* __restrict__ Wout,
    const float* __restrict__ bout, const int* __restrict__ batch,
    float* __restrict__ pooled)
{
  __shared__ float As[64][16];
  __shared__ float Bs[16][128];
  int tid = threadIdx.x;
  int tx = tid & 31, ty = tid >> 5;
  int rowBase = blockIdx.x * 64;
  float acc[8][4];
#pragma unroll
  for (int i = 0; i < 8; ++i) { acc[i][0]=0.f; acc[i][1]=0.f; acc[i][2]=0.f; acc[i][3]=0.f; }

  for (int kc = 0; kc < 8; ++kc) {
    int k0 = kc * 16;
    {
      int r = tid >> 2, kq = (tid & 3) * 4;
      int row = rowBase + r; if (row >= NND) row = NND - 1;
      *(float4*)&As[r][kq] = *(const float4*)&h2[(size_t)row * HD + k0 + kq];
    }
#pragma unroll
    for (int j = 0; j < 2; ++j) {
      int kk = (tid >> 5) + j * 8;
      int n = (tid & 31) * 4;
      *(float4*)&Bs[kk][n] = *(const float4*)&Wout[(k0 + kk) * HD + n];
    }
    __syncthreads();
#pragma unroll
    for (int kq = 0; kq < 4; ++kq) {
      float4 b0 = *(float4*)&Bs[kq*4+0][tx*4];
      float4 b1 = *(float4*)&Bs[kq*4+1][tx*4];
      float4 b2 = *(float4*)&Bs[kq*4+2][tx*4];
      float4 b3 = *(float4*)&Bs[kq*4+3][tx*4];
#pragma unroll
      for (int i = 0; i < 8; ++i) {
        float4 a = *(float4*)&As[ty*8+i][kq*4];
        acc[i][0] = fmaf(a.x,b0.x,fmaf(a.y,b1.x,fmaf(a.z,b2.x,fmaf(a.w,b3.x,acc[i][0]))));
        acc[i][1] = fmaf(a.x,b0.y,fmaf(a.y,b1.y,fmaf(a.z,b2.y,fmaf(a.w,b3.y,acc[i][1]))));
        acc[i][2] = fmaf(a.x,b0.z,fmaf(a.y,b1.z,fmaf(a.z,b2.z,fmaf(a.w,b3.z,acc[i][2]))));
        acc[i][3] = fmaf(a.x,b0.w,fmaf(a.y,b1.w,fmaf(a.z,b2.w,fmaf(a.w,b3.w,acc[i][3]))));
      }
    }
    __syncthreads();
  }

  int c0 = tx * 4;
  float4 bo = *(const float4*)&bout[c0];
  int prevg = -1;
  float r0 = 0.f, r1 = 0.f, r2 = 0.f, r3 = 0.f;
#pragma unroll
  for (int i = 0; i < 8; ++i) {
    int row = rowBase + ty*8 + i;
    if (row >= NND) break;
    int g = batch[row];
    float v0 = acc[i][0] + bo.x;
    float v1 = acc[i][1] + bo.y;
    float v2 = acc[i][2] + bo.z;
    float v3 = acc[i][3] + bo.w;
    if (g != prevg) {
      if (prevg >= 0) {
        atomicAdd(&pooled[prevg*HD + c0 + 0], r0);
        atomicAdd(&pooled[prevg*HD + c0 + 1], r1);
        atomicAdd(&pooled[prevg*HD + c0 + 2], r2);
        atomicAdd(&pooled[prevg*HD + c0 + 3], r3);
      }
      prevg = g; r0 = v0; r1 = v1; r2 = v2; r3 = v3;
    } else {
      r0 += v0; r1 += v1; r2 += v2; r3 += v3;
    }
  }
  if (prevg >= 0) {
    atomicAdd(&pooled[prevg*HD + c0 + 0], r0);
    atomicAdd(&pooled[prevg*HD + c0 + 1], r1);
    atomicAdd(&pooled[prevg*HD + c0 + 2], r2);
    atomicAdd(&pooled[prevg*HD + c0 + 3], r3);
  }
}

__global__ void k_final(const float* __restrict__ pooled, const float* __restrict__ cnt,
                        float* __restrict__ out) {
  int i = blockIdx.x * 256 + threadIdx.x;
  if (i < NG * HD) out[i] = pooled[i] / fmaxf(cnt[i >> 7], 1.0f);
}

extern "C" void kernel_launch(void* const* d_in, const int* in_sizes, int n_in,
                              void* d_out, int out_size, void* d_ws, size_t ws_size,
                              hipStream_t stream) {
  (void)in_sizes; (void)n_in; (void)out_size; (void)ws_size;
  const float* x     = (const float*)d_in[0];
  const int*   ei    = (const int*)d_in[1];
  const int*   batch = (const int*)d_in[2];
  const float* alpha = (const float*)d_in[3];
  const float* beta  = (const float*)d_in[4];
  const float* phase = (const float*)d_in[5];
  const float* Win   = (const float*)d_in[6];
  const float* bin   = (const float*)d_in[7];
  const float* gin   = (const float*)d_in[8];
  const float* bein  = (const float*)d_in[9];
  const float* Walt  = (const float*)d_in[10];
  const float* balt  = (const float*)d_in[11];
  const float* galt  = (const float*)d_in[12];
  const float* bealt = (const float*)d_in[13];
  const float* Wself = (const float*)d_in[14];
  const float* Wmsg  = (const float*)d_in[15];
  const float* bode  = (const float*)d_in[16];
  const float* Wint  = (const float*)d_in[17];
  const float* bint  = (const float*)d_in[18];
  const float* gint  = (const float*)d_in[19];
  const float* beint = (const float*)d_in[20];
  const float* Wout  = (const float*)d_in[21];
  const float* bout  = (const float*)d_in[22];
  float* out = (float*)d_out;

  const int* esrc = ei;
  const int* edst = ei + NED;

  size_t NH = (size_t)NND * HD;   // 6,400,000
  float* h      = (float*)d_ws;
  float* hacc   = h + NH;
  float* deginv = hacc + NH;
  float* weff   = deginv + NND;
  float* pooled = weff + HD * HD;
  float* cnt    = pooled + NG * HD;
  unsigned short* hbf = (unsigned short*)(cnt + NG);
  unsigned short* ybf = hbf + NH;
  unsigned short* Bt  = ybf + NH;          // 128*256
  int* degi   = (int*)(Bt + 128 * 256);
  int* rowptr = degi + NND;
  int* cursor = rowptr + (NND + 4);
  int* csrsrc = cursor + NND;

  hipMemsetAsync(degi, 0, NND * sizeof(int), stream);
  hipMemsetAsync(pooled, 0, NG * HD * sizeof(float), stream);

  k_hist   <<<(NED + 255) / 256, 256, 0, stream>>>(edst, degi);
  k_scan   <<<1, 1024, 0, stream>>>(degi, rowptr, cursor, deginv);
  k_scatter<<<(NED + 255) / 256, 256, 0, stream>>>(esrc, edst, cursor, csrsrc);
  k_cnt    <<<1, 64, 0, stream>>>(batch, cnt);
  k_weff   <<<(HD * HD + 255) / 256, 256, 0, stream>>>(Wint, weff);
  k_prepB  <<<128, 256, 0, stream>>>(Wself, Wmsg, Bt);
  k_init   <<<(NND + 31) / 32, 256, 0, stream>>>(x, Win, bin, gin, bein,
                                                 Walt, balt, galt, bealt,
                                                 alpha, beta, h, hbf);
  for (int step = 0; step < 8; ++step) {
    for (int stage = 0; stage < 4; ++stage) {
      const unsigned short* ainbf = (stage == 0) ? hbf : ybf;
      k_fused<<<(NND + 63) / 64, 256, 0, stream>>>(ainbf, rowptr, csrsrc, deginv,
                                                   Bt, bode, h, hacc, h, ybf, hbf, stage);
    }
  }
  k_interf<<<(NND + 63) / 64, 256, 0, stream>>>(h, weff, bint, gint, beint,
                                                alpha, beta, phase, hacc);
  k_out   <<<(NND + 63) / 64, 256, 0, stream>>>(hacc, Wout, bout, batch, pooled);
  k_final <<<(NG * HD + 255) / 256, 256, 0, stream>>>(pooled, cnt, out);
}